// Round 1
// 160.800 us; speedup vs baseline: 1.0658x; 1.0658x over previous
//
#include <hip/hip_runtime.h>
#include <hip/hip_bf16.h>
#include <cstdint>
#include <cstddef>

#define B_SZ 4
#define T_SZ 1024
#define N_SZ 1024
#define HID 1024
#define NHEADS 16
#define DHEAD 64

typedef __bf16 bf16x8 __attribute__((ext_vector_type(8)));
typedef __bf16 bf16x4 __attribute__((ext_vector_type(4)));
typedef float floatx4 __attribute__((ext_vector_type(4)));

#define LDT 72   // fallback gemm padding
// LDS leading dims MUST be multiples of 8 bf16 (16B): rows stay 16B-aligned so
// ds_read_b128/ds_write_b64 are emitted (R6 lesson: 66/68 broke b128 -> -21%).
#define LKV 72
#define LP  72

// log2(e)/sqrt(64), folded into Q at load; shift-free exp2-domain softmax
#define SM_SCALE_LOG2E 0.18033688011112042f

// global -> LDS async copy, 16B per lane (m97 staging path for the GEMM).
__device__ __forceinline__ void async_copy16(const void* gsrc, void* ldst) {
    __builtin_amdgcn_global_load_lds(
        (const __attribute__((address_space(1))) void*)(uintptr_t)gsrc,
        (__attribute__((address_space(3))) void*)(uintptr_t)ldst, 16, 0, 0);
}

// ---------------------------------------------------------------------------
// Convert fp32 -> bf16 for x(4M), enc(4M), Wq/Wk/Wv(1M each). (unchanged)
// ---------------------------------------------------------------------------
__global__ __launch_bounds__(256)
void cvt5_f32_bf16(const float* __restrict__ x, const float* __restrict__ enc,
                   const float* __restrict__ wq, const float* __restrict__ wk,
                   const float* __restrict__ wv,
                   __bf16* __restrict__ xb, __bf16* __restrict__ eb,
                   __bf16* __restrict__ wqb, __bf16* __restrict__ wkb,
                   __bf16* __restrict__ wvb)
{
#pragma unroll
    for (int c = 0; c < 8; ++c) {
        const int chunk = blockIdx.x * 8 + c;   // 0..5631, 2048 elems each
        const float* s; __bf16* d; int base;
        if (chunk < 2048)      { s = x;   d = xb;  base = chunk; }
        else if (chunk < 4096) { s = enc; d = eb;  base = chunk - 2048; }
        else if (chunk < 4608) { s = wq;  d = wqb; base = chunk - 4096; }
        else if (chunk < 5120) { s = wk;  d = wkb; base = chunk - 4608; }
        else                   { s = wv;  d = wvb; base = chunk - 5120; }
        const size_t off = (size_t)base * 2048 + (size_t)threadIdx.x * 8;
        const float4 a = *(const float4*)(s + off);
        const float4 b = *(const float4*)(s + off + 4);
        bf16x8 o;
        o[0] = (__bf16)a.x; o[1] = (__bf16)a.y; o[2] = (__bf16)a.z; o[3] = (__bf16)a.w;
        o[4] = (__bf16)b.x; o[5] = (__bf16)b.y; o[6] = (__bf16)b.z; o[7] = (__bf16)b.w;
        *(bf16x8*)(d + off) = o;
    }
}

// ---------------------------------------------------------------------------
// R9: fused QKV GEMM, 256x256 tile, BK=64, 8-phase counted-vmcnt schedule
// (T2+T3+T4+T5 from the 8-phase template; m201-class structure, ~1563 TF
// verified at 4k^3 vs ~900 for the old m97 2-barrier loop).
//
// Geometry: 512 thr = 8 waves as 2M x 4N. Per-wave C = 128x64, but split so
// each wave owns a 64-row stripe in EACH 128-row A-half and a 32-col stripe
// in EACH 128-col B-half -> every LDS half-region is last-read at a distinct
// phase and can be restaged one phase later (progressive freeing).
//
// LDS: 2 K-tile buffers x {A[2 halves][128x64], B[2][128x64]} = 128 KiB.
// XOR-chunk swizzle identical to R8 (counter-verified 0 bank conflicts):
// LDS[r][chunk c] holds source chunk c^(r&7); reads un-swizzle.
//
// Schedule per iteration (2 K-tiles kt0=2it in buf0, kt1=2it+1 in buf1):
//   phase: {ds_read quadrant frags; stage 1 half-tile (2 gload_lds);
//           BAR; setprio(1); 16 MFMA; setprio(0); [vmcnt(6) @ph4,ph8]; BAR}
//   reads:  ph1 A0,B0 | ph2 B1 | ph3 A1 | ph4 - | ph5-8 same on buf1
//   stages: ph1 b1.A1<-kt1 | ph2 b0.A0<-kt0+2 | ph3 b0.B0 | ph4 b0.B1
//         | ph5 b0.A1      | ph6 b1.A0<-kt1+2 | ph7 b1.B0 | ph8 b1.B1
// Proof of RAW: vmcnt(6)@ph4 covers issues <=ph1 (prev ph6,7,8 + this ph1);
// vmcnt(6)@ph8 covers <=ph5 (this ph2..5). Every region completes before its
// first read; every stage targets a region last-read the previous phase (WAR
// safe behind the phase barrier). Tail clamps prefetch kt (L2-hot, harmless).
// ---------------------------------------------------------------------------
#define PBAR() do {                              \
    asm volatile("" ::: "memory");               \
    __builtin_amdgcn_s_barrier();                \
    __builtin_amdgcn_sched_barrier(0);           \
} while (0)

#define MFMA_Q(QM, QN, BREG) do {                                             \
    __builtin_amdgcn_s_setprio(1);                                            \
    _Pragma("unroll")                                                         \
    for (int mf_ = 0; mf_ < 4; ++mf_) {                                       \
        _Pragma("unroll")                                                     \
        for (int nf_ = 0; nf_ < 2; ++nf_) {                                   \
            acc[QM][QN][mf_][nf_] = __builtin_amdgcn_mfma_f32_16x16x32_bf16(  \
                a[mf_][0], BREG[nf_][0], acc[QM][QN][mf_][nf_], 0, 0, 0);     \
            acc[QM][QN][mf_][nf_] = __builtin_amdgcn_mfma_f32_16x16x32_bf16(  \
                a[mf_][1], BREG[nf_][1], acc[QM][QN][mf_][nf_], 0, 0, 0);     \
        }                                                                     \
    }                                                                         \
    __builtin_amdgcn_s_setprio(0);                                            \
} while (0)

#define LOAD_A(BUF, HALF) do {                                                \
    _Pragma("unroll")                                                         \
    for (int mf_ = 0; mf_ < 4; ++mf_) {                                       \
        a[mf_][0] = ldsA(BUF, HALF, mf_, 0);                                  \
        a[mf_][1] = ldsA(BUF, HALF, mf_, 1);                                  \
    }                                                                         \
} while (0)

#define LOAD_B(DST, BUF, HALF) do {                                           \
    _Pragma("unroll")                                                         \
    for (int nf_ = 0; nf_ < 2; ++nf_) {                                       \
        DST[nf_][0] = ldsB(BUF, HALF, nf_, 0);                                \
        DST[nf_][1] = ldsB(BUF, HALF, nf_, 1);                                \
    }                                                                         \
} while (0)

__global__ __launch_bounds__(512, 2)
void gemm3_256_8ph(const __bf16* __restrict__ xb, const __bf16* __restrict__ eb,
                   const __bf16* __restrict__ wqb, const __bf16* __restrict__ wkb,
                   const __bf16* __restrict__ wvb,
                   const float* __restrict__ bq, const float* __restrict__ bk,
                   const float* __restrict__ bv,
                   __bf16* __restrict__ qo, __bf16* __restrict__ ko,
                   __bf16* __restrict__ vo)
{
    // [buf][half][128 rows x 64 cols] bf16 = 16 KiB per region, 128 KiB total
    __shared__ __align__(16) __bf16 AS[2][2][8192];
    __shared__ __align__(16) __bf16 BS[2][2][8192];

    // grid = 192 = 48 M-tiles (Q:0-15, K:16-31, V:32-47) x 4 N-tiles.
    // Bijective XCD swizzle, chunk = 192/8 = 24: each XCD owns 6 M-tiles with
    // all 4 N-tiles contiguous -> A-panel fetched once per chip, W L2-shared.
    const int bid = blockIdx.x;
    const int swz = (bid & 7) * 24 + (bid >> 3);
    const int mt  = swz >> 2;          // 0..47
    const int nt  = swz & 3;           // 0..3
    const int z   = mt >> 4;
    const int bm  = (mt & 15) << 8;    // *256
    const int bn  = nt << 8;

    const __bf16* A; const __bf16* W; const float* bias; __bf16* C;
    if (z == 0)      { A = xb; W = wqb; bias = bq; C = qo; }
    else if (z == 1) { A = eb; W = wkb; bias = bk; C = ko; }
    else             { A = eb; W = wvb; bias = bv; C = vo; }

    const int tid  = threadIdx.x;      // 0..511
    const int lane = tid & 63;
    const int wid  = tid >> 6;         // 0..7
    const int l15  = lane & 15;
    const int quad = lane >> 4;
    const int wmid = wid >> 2;         // 0..1  (M stripe)
    const int wnid = wid & 3;          // 0..3  (N stripe)

    // staging: thread t covers 16B at row sr=t>>3 (+64 on round 1), chunk t&7
    const int sr  = tid >> 3;          // 0..63
    const int sch = tid & 7;

    // stage one 128x64 half-tile (2 x global_load_lds per thread)
    auto stage2 = [&](const __bf16* src, __bf16* dst, int gRow0, int kt) {
        const int c = (sch ^ (sr & 7)) << 3;   // pre-swizzled source chunk
        async_copy16(src + (size_t)(gRow0 + sr) * HID + kt * 64 + c,
                     (char*)dst + tid * 16);
        async_copy16(src + (size_t)(gRow0 + sr + 64) * HID + kt * 64 + c,
                     (char*)dst + 8192 + tid * 16);
    };

    // fragment reads (un-swizzle: phys chunk = (kk*4+quad) ^ (row&7))
    auto ldsA = [&](int buf, int half, int mf, int kk) -> bf16x8 {
        const int r = wmid * 64 + mf * 16 + l15;
        return *(const bf16x8*)((const char*)&AS[buf][half][0] + r * 128 +
                                (((kk * 4 + quad) ^ (r & 7)) << 4));
    };
    auto ldsB = [&](int buf, int half, int nf, int kk) -> bf16x8 {
        const int r = wnid * 32 + nf * 16 + l15;
        return *(const bf16x8*)((const char*)&BS[buf][half][0] + r * 128 +
                                (((kk * 4 + quad) ^ (r & 7)) << 4));
    };

    bf16x8 a[4][2], b0[2][2], b1[2][2];
    floatx4 acc[2][2][4][2];
#pragma unroll
    for (int i = 0; i < 2; ++i)
#pragma unroll
        for (int j = 0; j < 2; ++j)
#pragma unroll
            for (int m = 0; m < 4; ++m)
#pragma unroll
                for (int n = 0; n < 2; ++n)
                    acc[i][j][m][n] = (floatx4)(0.0f);

    // ---- prologue: kt0 (4 halves) + kt1 {A0,B0,B1}; keep kt1 in flight ----
    stage2(A, &AS[0][0][0], bm,       0);
    stage2(W, &BS[0][0][0], bn,       0);
    stage2(W, &BS[0][1][0], bn + 128, 0);
    stage2(A, &AS[0][1][0], bm + 128, 0);
    stage2(A, &AS[1][0][0], bm,       1);
    stage2(W, &BS[1][0][0], bn,       1);
    stage2(W, &BS[1][1][0], bn + 128, 1);
    asm volatile("s_waitcnt vmcnt(6)" ::: "memory");
    PBAR();

#pragma unroll 1
    for (int it = 0; it < 8; ++it) {
        const int kt1 = 2 * it + 1;
        const int kta = (it < 7) ? 2 * it + 2 : 14;   // tail: clamp (L2-hot junk)
        const int ktb = (it < 7) ? 2 * it + 3 : 15;

        // phase 1: read buf0.{A0,B0}; stage b1.A1<-kt1; acc[0][0]
        LOAD_A(0, 0);
        LOAD_B(b0, 0, 0);
        stage2(A, &AS[1][1][0], bm + 128, kt1);
        PBAR();
        MFMA_Q(0, 0, b0);
        PBAR();
        // phase 2: read buf0.B1; stage b0.A0<-kta; acc[0][1]
        LOAD_B(b1, 0, 1);
        stage2(A, &AS[0][0][0], bm, kta);
        PBAR();
        MFMA_Q(0, 1, b1);
        PBAR();
        // phase 3: read buf0.A1; stage b0.B0<-kta; acc[1][1]
        LOAD_A(0, 1);
        stage2(W, &BS[0][0][0], bn, kta);
        PBAR();
        MFMA_Q(1, 1, b1);
        PBAR();
        // phase 4: (regs only); stage b0.B1<-kta; acc[1][0]; counted wait
        stage2(W, &BS[0][1][0], bn + 128, kta);
        PBAR();
        MFMA_Q(1, 0, b0);
        asm volatile("s_waitcnt vmcnt(6)" ::: "memory");
        PBAR();
        // phase 5: read buf1.{A0,B0}; stage b0.A1<-kta; acc[0][0]
        LOAD_A(1, 0);
        LOAD_B(b0, 1, 0);
        stage2(A, &AS[0][1][0], bm + 128, kta);
        PBAR();
        MFMA_Q(0, 0, b0);
        PBAR();
        // phase 6: read buf1.B1; stage b1.A0<-ktb; acc[0][1]
        LOAD_B(b1, 1, 1);
        stage2(A, &AS[1][0][0], bm, ktb);
        PBAR();
        MFMA_Q(0, 1, b1);
        PBAR();
        // phase 7: read buf1.A1; stage b1.B0<-ktb; acc[1][1]
        LOAD_A(1, 1);
        stage2(W, &BS[1][0][0], bn, ktb);
        PBAR();
        MFMA_Q(1, 1, b1);
        PBAR();
        // phase 8: (regs only); stage b1.B1<-ktb; acc[1][0]; counted wait
        stage2(W, &BS[1][1][0], bn + 128, ktb);
        PBAR();
        MFMA_Q(1, 0, b0);
        asm volatile("s_waitcnt vmcnt(6)" ::: "memory");
        PBAR();
    }

    // ---- epilogue: C/D layout col=l15, row=quad*4+reg [m89/m91-verified] ----
#pragma unroll
    for (int qn = 0; qn < 2; ++qn)
#pragma unroll
        for (int nf = 0; nf < 2; ++nf) {
            const int n = bn + qn * 128 + wnid * 32 + nf * 16 + l15;
            const float bias_f = bias[n];
#pragma unroll
            for (int qm = 0; qm < 2; ++qm)
#pragma unroll
                for (int mf = 0; mf < 4; ++mf) {
                    const int m0 = bm + qm * 128 + wmid * 64 + mf * 16 + quad * 4;
#pragma unroll
                    for (int r = 0; r < 4; ++r)
                        C[(size_t)(m0 + r) * HID + n] =
                            (__bf16)(acc[qm][qn][mf][nf][r] + bias_f);
                }
        }
}

#undef LOAD_A
#undef LOAD_B
#undef MFMA_Q
#undef PBAR

// ---------------------------------------------------------------------------
// Fallback GEMM (fp32 inputs staged+converted through LDS) for small ws.
// ---------------------------------------------------------------------------
__global__ __launch_bounds__(256)
void gemm_bt_bias_f32in(const float* __restrict__ A,
                        const float* __restrict__ W,
                        const float* __restrict__ bias,
                        __hip_bfloat16* __restrict__ C)
{
    constexpr int K = HID;
    __shared__ __align__(16) __hip_bfloat16 As[128 * LDT];
    __shared__ __align__(16) __hip_bfloat16 Bs[128 * LDT];

    const int tid  = threadIdx.x;
    const int wave = tid >> 6;
    const int lane = tid & 63;
    const int bm = blockIdx.y * 128;
    const int bn = blockIdx.x * 128;
    const int wm = (wave >> 1) * 64;
    const int wn = (wave & 1) * 64;

    floatx4 acc[4][4];
#pragma unroll
    for (int i = 0; i < 4; ++i)
#pragma unroll
        for (int j = 0; j < 4; ++j)
            acc[i][j] = (floatx4)(0.0f);

    const int lr = tid >> 4;
    const int lc = (tid & 15) * 4;

    for (int k0 = 0; k0 < K; k0 += 64) {
#pragma unroll
        for (int qq = 0; qq < 8; ++qq) {
            const int r = lr + qq * 16;
            const float4 a4 = *(const float4*)(A + (size_t)(bm + r) * K + k0 + lc);
            const float4 w4 = *(const float4*)(W + (size_t)(bn + r) * K + k0 + lc);
            bf16x4 av, wv;
            av[0] = (__bf16)a4.x; av[1] = (__bf16)a4.y; av[2] = (__bf16)a4.z; av[3] = (__bf16)a4.w;
            wv[0] = (__bf16)w4.x; wv[1] = (__bf16)w4.y; wv[2] = (__bf16)w4.z; wv[3] = (__bf16)w4.w;
            *(bf16x4*)(As + r * LDT + lc) = av;
            *(bf16x4*)(Bs + r * LDT + lc) = wv;
        }
        __syncthreads();
#pragma unroll
        for (int kk = 0; kk < 2; ++kk) {
            const int krow = kk * 32 + (lane >> 4) * 8;
            const int mrow = wm + (lane & 15);
            const int nrow = wn + (lane & 15);
            bf16x8 af[4], bfr[4];
#pragma unroll
            for (int i = 0; i < 4; ++i) {
                af[i]  = *(const bf16x8*)(As + (mrow + i * 16) * LDT + krow);
                bfr[i] = *(const bf16x8*)(Bs + (nrow + i * 16) * LDT + krow);
            }
#pragma unroll
            for (int mi = 0; mi < 4; ++mi)
#pragma unroll
                for (int ni = 0; ni < 4; ++ni)
                    acc[mi][ni] = __builtin_amdgcn_mfma_f32_16x16x32_bf16(
                        af[mi], bfr[ni], acc[mi][ni], 0, 0, 0);
        }
        __syncthreads();
    }

    const int crow0 = bm + wm + (lane >> 4) * 4;
    const int ccol0 = bn + wn + (lane & 15);
#pragma unroll
    for (int ni = 0; ni < 4; ++ni) {
        const int n = ccol0 + ni * 16;
        const float bias_f = bias[n];
#pragma unroll
        for (int mi = 0; mi < 4; ++mi) {
#pragma unroll
            for (int r = 0; r < 4; ++r) {
                const int m = crow0 + mi * 16 + r;
                C[(size_t)m * HID + n] = __float2bfloat16(acc[mi][ni][r] + bias_f);
            }
        }
    }
}

// ---------------------------------------------------------------------------
// Flash attention v4 (unchanged from R7; ~38-45 us): transposed-S data flow,
// shift-free exp2 softmax, double-buffered K/V, one barrier/tile, balanced
// block pairing. grid = 512; block = 256.
// ---------------------------------------------------------------------------
__global__ __launch_bounds__(256)
void attn_flash_mfma_v4(const __bf16* __restrict__ q,
                        const __bf16* __restrict__ k,
                        const __bf16* __restrict__ v,
                        float* __restrict__ out)
{
    __shared__ __align__(16) __bf16 Ks[2][64 * LKV];    // [n][d]
    __shared__ __align__(16) __bf16 Vt[2][64 * LKV];    // [d][n]
    __shared__ __align__(16) __bf16 Ps[4][32 * LP];     // per-wave P [m][n]

    const int tid  = threadIdx.x;
    const int wave = tid >> 6;
    const int lane = tid & 63;
    const int l15  = lane & 15;
    const int quad = lane >> 4;

    const int bx = blockIdx.x;           // 0..511
    const int jj = bx & 7;
    const int bt = ((bx >> 8) & 1) ? jj : 7 - jj;   // pair-balanced LJF
    const int bh = bx >> 3;              // 0..63
    const int h  = bh & (NHEADS - 1);
    const int b  = bh >> 4;
    const int t0 = bt * 128;

    const __bf16* kbase = k + (size_t)b * N_SZ * HID + h * DHEAD;
    const __bf16* vbase = v + (size_t)b * N_SZ * HID + h * DHEAD;

    // ---- Q rows to registers (B-frag of S^T), pre-scaled ----
    bf16x8 qf[2][2];
    {
        const __bf16* qb = q + (size_t)(b * T_SZ + t0 + wave * 32) * HID + h * DHEAD;
#pragma unroll
        for (int g = 0; g < 2; ++g)
#pragma unroll
            for (int kk = 0; kk < 2; ++kk) {
                const bf16x8 raw = *(const bf16x8*)(qb + (size_t)(g * 16 + l15) * HID
                                                    + kk * 32 + quad * 8);
#pragma unroll
                for (int j = 0; j < 8; ++j)
                    qf[g][kk][j] = (__bf16)((float)raw[j] * SM_SCALE_LOG2E);
            }
    }

    const int kr = tid >> 3;
    const int kc = (tid & 7) * 8;
    const int vn = tid & 63;
    const int vd = (tid >> 6) * 8;

#pragma unroll
    for (int p = 0; p < 2; ++p) {
        *(bf16x8*)(&Ks[0][(kr + p * 32) * LKV + kc]) =
            *(const bf16x8*)(kbase + (size_t)(kr + p * 32) * HID + kc);
        const bf16x8 vv = *(const bf16x8*)(vbase + (size_t)vn * HID + vd + p * 32);
#pragma unroll
        for (int j = 0; j < 8; ++j)
            Vt[0][(vd + p * 32 + j) * LKV + vn] = vv[j];
    }
    __syncthreads();

    float lsum[2] = {0.f, 0.f};
    floatx4 oacc[2][4];
#pragma unroll
    for (int g = 0; g < 2; ++g)
#pragma unroll
        for (int nd = 0; nd < 4; ++nd) oacc[g][nd] = (floatx4)(0.0f);

    __bf16* pw = &Ps[wave][0];
    const int ntiles = 2 * bt + 2;

    for (int it = 0; it < ntiles; ++it) {
        const int bi = it & 1;
        const int n0 = it * 64;

        bf16x8 nk0, nk1, nv0, nv1;
        const bool pf = (it + 1 < ntiles);
        if (pf) {
            const int nn0 = n0 + 64;
            nk0 = *(const bf16x8*)(kbase + (size_t)(nn0 + kr) * HID + kc);
            nk1 = *(const bf16x8*)(kbase + (size_t)(nn0 + kr + 32) * HID + kc);
            nv0 = *(const bf16x8*)(vbase + (size_t)(nn0 + vn) * HID + vd);
            nv1 = *(const bf16x8*)(vbase + (size_t)(nn0 + vn) * HID + vd + 32);
        }

        // ---- S^T = K @ Q^T : C/D col=m(l15), row=n(quad*4+r) ----
        floatx4 st[2][4];
#pragma unroll
        for (int g = 0; g < 2; ++g)
#pragma unroll
            for (int ni = 0; ni < 4; ++ni) st[g][ni] = (floatx4)(0.0f);
        const __bf16* ksb = &Ks[bi][0];
#pragma unroll
        for (int kk = 0; kk < 2; ++kk) {
            const int ko = kk * 32 + quad * 8;
#pragma unroll
            for (int ni = 0; ni < 4; ++ni) {
                const bf16x8 af = *(const bf16x8*)(ksb + (ni * 16 + l15) * LKV + ko);
                st[0][ni] = __builtin_amdgcn_mfma_f32_16x16x32_bf16(af, qf[0][kk], st[0][ni], 0, 0, 0);
                st[1][ni] = __builtin_amdgcn_mfma_f32_16x16x32_bf16(af, qf[1][kk], st[1][ni], 0, 0, 0);
            }
        }

        // ---- shift-free softmax; packed b64 P-writes; lane-local lsum ----
        const bool msk = (it >= 2 * bt);
#pragma unroll
        for (int g = 0; g < 2; ++g) {
            const int tq = t0 + wave * 32 + g * 16 + l15;
#pragma unroll
            for (int ni = 0; ni < 4; ++ni) {
                bf16x4 pk;
#pragma unroll
                for (int r = 0; r < 4; ++r) {
                    float p = exp2f(st[g][ni][r]);
                    if (msk) {
                        const int nn = n0 + ni * 16 + quad * 4 + r;
                        p = (nn > tq) ? 0.f : p;
                    }
                    lsum[g] += p;
                    pk[r] = (__bf16)p;
                }
                *(bf16x4*)(pw + (g * 16 + l15) * LP + ni * 16 + quad * 4) = pk;
            }
        }

        // ---- O^T += Vt @ P : C/D col=m(l15), row=d(quad*4+r) ----
        const __bf16* vtb = &Vt[bi][0];
#pragma unroll
        for (int kk = 0; kk < 2; ++kk) {
            const int ko = kk * 32 + quad * 8;
            const bf16x8 bp0 = *(const bf16x8*)(pw + l15 * LP + ko);
            const bf16x8 bp1 = *(const bf16x8*)(pw + (16 + l15) * LP + ko);
#pragma unroll
            for (int nd = 0; nd < 4; ++nd) {
                const bf16x8 av = *(const bf16x8*)(vtb + (nd * 16 + l15) * LKV + ko);
                oacc[0][nd] = __builtin_amdgcn_mfma_f32_16x16x32_bf16(av, bp0, oacc[0][nd], 0, 0, 0);
                oacc[1][nd] = __builtin_amdgcn_mfma_f32_16x16x32_bf16(av, bp1, oacc[1][nd], 0, 0, 0);
            }
        }

        if (pf) {
            const int wb = bi ^ 1;
            *(bf16x8*)(&Ks[wb][kr * LKV + kc]) = nk0;
            *(bf16x8*)(&Ks[wb][(kr + 32) * LKV + kc]) = nk1;
#pragma unroll
            for (int j = 0; j < 8; ++j) {
                Vt[wb][(vd + j) * LKV + vn] = nv0[j];
                Vt[wb][(vd + 32 + j) * LKV + vn] = nv1[j];
            }
        }
        __syncthreads();
    }

    // ---- epilogue ----
#pragma unroll
    for (int g = 0; g < 2; ++g) {
        lsum[g] += __shfl_xor(lsum[g], 16, 64);
        lsum[g] += __shfl_xor(lsum[g], 32, 64);
    }
#pragma unroll
    for (int g = 0; g < 2; ++g) {
        const float invl = 1.0f / lsum[g];
        const int trow = t0 + wave * 32 + g * 16 + l15;
        float* ob = out + (size_t)(b * T_SZ + trow) * HID + h * DHEAD + quad * 4;
#pragma unroll
        for (int nd = 0; nd < 4; ++nd) {
            float4 o4;
            o4.x = oacc[g][nd][0] * invl;
            o4.y = oacc[g][nd][1] * invl;
            o4.z = oacc[g][nd][2] * invl;
            o4.w = oacc[g][nd][3] * invl;
            *(float4*)(ob + nd * 16) = o4;
        }
    }
}

extern "C" void kernel_launch(void* const* d_in, const int* in_sizes, int n_in,
                              void* d_out, int out_size, void* d_ws, size_t ws_size,
                              hipStream_t stream) {
    const float* x   = (const float*)d_in[0];
    const float* enc = (const float*)d_in[1];
    const float* Wq  = (const float*)d_in[2];
    const float* bq  = (const float*)d_in[3];
    const float* Wk  = (const float*)d_in[4];
    const float* bk  = (const float*)d_in[5];
    const float* Wv  = (const float*)d_in[6];
    const float* bv  = (const float*)d_in[7];
    float* out = (float*)d_out;

    char* ws = (char*)d_ws;
    const size_t MiB = 1024 * 1024;
    __bf16* q_ws = (__bf16*)(ws);
    __bf16* k_ws = (__bf16*)(ws + 8 * MiB);
    __bf16* v_ws = (__bf16*)(ws + 16 * MiB);

    const dim3 blk(256);
    if (ws_size >= 46 * MiB) {
        __bf16* xb  = (__bf16*)(ws + 24 * MiB);
        __bf16* eb  = (__bf16*)(ws + 32 * MiB);
        __bf16* wqb = (__bf16*)(ws + 40 * MiB);
        __bf16* wkb = (__bf16*)(ws + 42 * MiB);
        __bf16* wvb = (__bf16*)(ws + 44 * MiB);
        cvt5_f32_bf16<<<dim3(704), blk, 0, stream>>>(x, enc, Wq, Wk, Wv,
                                                     xb, eb, wqb, wkb, wvb);
        gemm3_256_8ph<<<dim3(192), dim3(512), 0, stream>>>(
            xb, eb, wqb, wkb, wvb, bq, bk, bv, q_ws, k_ws, v_ws);
    } else {
        const dim3 gg(HID / 128, (B_SZ * T_SZ) / 128);
        gemm_bt_bias_f32in<<<gg, blk, 0, stream>>>(x,   Wq, bq, (__hip_bfloat16*)q_ws);
        gemm_bt_bias_f32in<<<gg, blk, 0, stream>>>(enc, Wk, bk, (__hip_bfloat16*)k_ws);
        gemm_bt_bias_f32in<<<gg, blk, 0, stream>>>(enc, Wv, bv, (__hip_bfloat16*)v_ws);
    }

    attn_flash_mfma_v4<<<dim3(512), blk, 0, stream>>>(q_ws, k_ws, v_ws, out);
}

// Round 2
// 154.121 us; speedup vs baseline: 1.1120x; 1.0433x over previous
//
#include <hip/hip_runtime.h>
#include <hip/hip_bf16.h>
#include <cstdint>
#include <cstddef>

#define B_SZ 4
#define T_SZ 1024
#define N_SZ 1024
#define HID 1024
#define NHEADS 16
#define DHEAD 64

typedef __bf16 bf16x8 __attribute__((ext_vector_type(8)));
typedef __bf16 bf16x4 __attribute__((ext_vector_type(4)));
typedef __bf16 bf16x2 __attribute__((ext_vector_type(2)));
typedef float floatx4 __attribute__((ext_vector_type(4)));

#define LDT 72   // fallback gemm padding

// log2(e)/sqrt(64), folded into Q at load; shift-free exp2-domain softmax
#define SM_SCALE_LOG2E 0.18033688011112042f

// attn LDS rows are 128B (64 bf16). Modular column-rotation swizzle:
// col' = (col + (row&7)*16) mod 128. Verified bank-optimal for ALL access
// shapes used here (b128 r/w, b64 write, b32 write); XOR-bit4 would collapse
// the P b64-write columns to 4 slots (4x conflict) -- ADD-rotation does not.
#define SWZ(row, colbyte) (((row) << 7) + ((((colbyte) + (((row) & 7) << 4))) & 127))

// global -> LDS async copy, 16B per lane (m97 staging path for the GEMM).
__device__ __forceinline__ void async_copy16(const void* gsrc, void* ldst) {
    __builtin_amdgcn_global_load_lds(
        (const __attribute__((address_space(1))) void*)(uintptr_t)gsrc,
        (__attribute__((address_space(3))) void*)(uintptr_t)ldst, 16, 0, 0);
}

// ---------------------------------------------------------------------------
// Convert fp32 -> bf16 for x(4M), enc(4M), Wq/Wk/Wv(1M each). (unchanged)
// ---------------------------------------------------------------------------
__global__ __launch_bounds__(256)
void cvt5_f32_bf16(const float* __restrict__ x, const float* __restrict__ enc,
                   const float* __restrict__ wq, const float* __restrict__ wk,
                   const float* __restrict__ wv,
                   __bf16* __restrict__ xb, __bf16* __restrict__ eb,
                   __bf16* __restrict__ wqb, __bf16* __restrict__ wkb,
                   __bf16* __restrict__ wvb)
{
#pragma unroll
    for (int c = 0; c < 8; ++c) {
        const int chunk = blockIdx.x * 8 + c;   // 0..5631, 2048 elems each
        const float* s; __bf16* d; int base;
        if (chunk < 2048)      { s = x;   d = xb;  base = chunk; }
        else if (chunk < 4096) { s = enc; d = eb;  base = chunk - 2048; }
        else if (chunk < 4608) { s = wq;  d = wqb; base = chunk - 4096; }
        else if (chunk < 5120) { s = wk;  d = wkb; base = chunk - 4608; }
        else                   { s = wv;  d = wvb; base = chunk - 5120; }
        const size_t off = (size_t)base * 2048 + (size_t)threadIdx.x * 8;
        const float4 a = *(const float4*)(s + off);
        const float4 b = *(const float4*)(s + off + 4);
        bf16x8 o;
        o[0] = (__bf16)a.x; o[1] = (__bf16)a.y; o[2] = (__bf16)a.z; o[3] = (__bf16)a.w;
        o[4] = (__bf16)b.x; o[5] = (__bf16)b.y; o[6] = (__bf16)b.z; o[7] = (__bf16)b.w;
        *(bf16x8*)(d + off) = o;
    }
}

// ---------------------------------------------------------------------------
// Fused QKV GEMM, 256x256 tile, BK=64, 8-phase counted-vmcnt schedule.
// (R9 structure, unchanged this round -- frozen for attribution.)
// ---------------------------------------------------------------------------
#define PBAR() do {                              \
    asm volatile("" ::: "memory");               \
    __builtin_amdgcn_s_barrier();                \
    __builtin_amdgcn_sched_barrier(0);           \
} while (0)

#define MFMA_Q(QM, QN, BREG) do {                                             \
    __builtin_amdgcn_s_setprio(1);                                            \
    _Pragma("unroll")                                                         \
    for (int mf_ = 0; mf_ < 4; ++mf_) {                                       \
        _Pragma("unroll")                                                     \
        for (int nf_ = 0; nf_ < 2; ++nf_) {                                   \
            acc[QM][QN][mf_][nf_] = __builtin_amdgcn_mfma_f32_16x16x32_bf16(  \
                a[mf_][0], BREG[nf_][0], acc[QM][QN][mf_][nf_], 0, 0, 0);     \
            acc[QM][QN][mf_][nf_] = __builtin_amdgcn_mfma_f32_16x16x32_bf16(  \
                a[mf_][1], BREG[nf_][1], acc[QM][QN][mf_][nf_], 0, 0, 0);     \
        }                                                                     \
    }                                                                         \
    __builtin_amdgcn_s_setprio(0);                                            \
} while (0)

#define LOAD_A(BUF, HALF) do {                                                \
    _Pragma("unroll")                                                         \
    for (int mf_ = 0; mf_ < 4; ++mf_) {                                       \
        a[mf_][0] = ldsA(BUF, HALF, mf_, 0);                                  \
        a[mf_][1] = ldsA(BUF, HALF, mf_, 1);                                  \
    }                                                                         \
} while (0)

#define LOAD_B(DST, BUF, HALF) do {                                           \
    _Pragma("unroll")                                                         \
    for (int nf_ = 0; nf_ < 2; ++nf_) {                                       \
        DST[nf_][0] = ldsB(BUF, HALF, nf_, 0);                                \
        DST[nf_][1] = ldsB(BUF, HALF, nf_, 1);                                \
    }                                                                         \
} while (0)

__global__ __launch_bounds__(512, 2)
void gemm3_256_8ph(const __bf16* __restrict__ xb, const __bf16* __restrict__ eb,
                   const __bf16* __restrict__ wqb, const __bf16* __restrict__ wkb,
                   const __bf16* __restrict__ wvb,
                   const float* __restrict__ bq, const float* __restrict__ bk,
                   const float* __restrict__ bv,
                   __bf16* __restrict__ qo, __bf16* __restrict__ ko,
                   __bf16* __restrict__ vo)
{
    // [buf][half][128 rows x 64 cols] bf16 = 16 KiB per region, 128 KiB total
    __shared__ __align__(16) __bf16 AS[2][2][8192];
    __shared__ __align__(16) __bf16 BS[2][2][8192];

    const int bid = blockIdx.x;
    const int swz = (bid & 7) * 24 + (bid >> 3);
    const int mt  = swz >> 2;          // 0..47
    const int nt  = swz & 3;           // 0..3
    const int z   = mt >> 4;
    const int bm  = (mt & 15) << 8;    // *256
    const int bn  = nt << 8;

    const __bf16* A; const __bf16* W; const float* bias; __bf16* C;
    if (z == 0)      { A = xb; W = wqb; bias = bq; C = qo; }
    else if (z == 1) { A = eb; W = wkb; bias = bk; C = ko; }
    else             { A = eb; W = wvb; bias = bv; C = vo; }

    const int tid  = threadIdx.x;      // 0..511
    const int lane = tid & 63;
    const int wid  = tid >> 6;         // 0..7
    const int l15  = lane & 15;
    const int quad = lane >> 4;
    const int wmid = wid >> 2;         // 0..1  (M stripe)
    const int wnid = wid & 3;          // 0..3  (N stripe)

    const int sr  = tid >> 3;          // 0..63
    const int sch = tid & 7;

    auto stage2 = [&](const __bf16* src, __bf16* dst, int gRow0, int kt) {
        const int c = (sch ^ (sr & 7)) << 3;   // pre-swizzled source chunk
        async_copy16(src + (size_t)(gRow0 + sr) * HID + kt * 64 + c,
                     (char*)dst + tid * 16);
        async_copy16(src + (size_t)(gRow0 + sr + 64) * HID + kt * 64 + c,
                     (char*)dst + 8192 + tid * 16);
    };

    auto ldsA = [&](int buf, int half, int mf, int kk) -> bf16x8 {
        const int r = wmid * 64 + mf * 16 + l15;
        return *(const bf16x8*)((const char*)&AS[buf][half][0] + r * 128 +
                                (((kk * 4 + quad) ^ (r & 7)) << 4));
    };
    auto ldsB = [&](int buf, int half, int nf, int kk) -> bf16x8 {
        const int r = wnid * 32 + nf * 16 + l15;
        return *(const bf16x8*)((const char*)&BS[buf][half][0] + r * 128 +
                                (((kk * 4 + quad) ^ (r & 7)) << 4));
    };

    bf16x8 a[4][2], b0[2][2], b1[2][2];
    floatx4 acc[2][2][4][2];
#pragma unroll
    for (int i = 0; i < 2; ++i)
#pragma unroll
        for (int j = 0; j < 2; ++j)
#pragma unroll
            for (int m = 0; m < 4; ++m)
#pragma unroll
                for (int n = 0; n < 2; ++n)
                    acc[i][j][m][n] = (floatx4)(0.0f);

    // ---- prologue: kt0 (4 halves) + kt1 {A0,B0,B1}; keep kt1 in flight ----
    stage2(A, &AS[0][0][0], bm,       0);
    stage2(W, &BS[0][0][0], bn,       0);
    stage2(W, &BS[0][1][0], bn + 128, 0);
    stage2(A, &AS[0][1][0], bm + 128, 0);
    stage2(A, &AS[1][0][0], bm,       1);
    stage2(W, &BS[1][0][0], bn,       1);
    stage2(W, &BS[1][1][0], bn + 128, 1);
    asm volatile("s_waitcnt vmcnt(6)" ::: "memory");
    PBAR();

#pragma unroll 1
    for (int it = 0; it < 8; ++it) {
        const int kt1 = 2 * it + 1;
        const int kta = (it < 7) ? 2 * it + 2 : 14;   // tail: clamp (L2-hot junk)
        const int ktb = (it < 7) ? 2 * it + 3 : 15;

        // phase 1: read buf0.{A0,B0}; stage b1.A1<-kt1; acc[0][0]
        LOAD_A(0, 0);
        LOAD_B(b0, 0, 0);
        stage2(A, &AS[1][1][0], bm + 128, kt1);
        PBAR();
        MFMA_Q(0, 0, b0);
        PBAR();
        // phase 2: read buf0.B1; stage b0.A0<-kta; acc[0][1]
        LOAD_B(b1, 0, 1);
        stage2(A, &AS[0][0][0], bm, kta);
        PBAR();
        MFMA_Q(0, 1, b1);
        PBAR();
        // phase 3: read buf0.A1; stage b0.B0<-kta; acc[1][1]
        LOAD_A(0, 1);
        stage2(W, &BS[0][0][0], bn, kta);
        PBAR();
        MFMA_Q(1, 1, b1);
        PBAR();
        // phase 4: (regs only); stage b0.B1<-kta; acc[1][0]; counted wait
        stage2(W, &BS[0][1][0], bn + 128, kta);
        PBAR();
        MFMA_Q(1, 0, b0);
        asm volatile("s_waitcnt vmcnt(6)" ::: "memory");
        PBAR();
        // phase 5: read buf1.{A0,B0}; stage b0.A1<-kta; acc[0][0]
        LOAD_A(1, 0);
        LOAD_B(b0, 1, 0);
        stage2(A, &AS[0][1][0], bm + 128, kta);
        PBAR();
        MFMA_Q(0, 0, b0);
        PBAR();
        // phase 6: read buf1.B1; stage b1.A0<-ktb; acc[0][1]
        LOAD_B(b1, 1, 1);
        stage2(A, &AS[1][0][0], bm, ktb);
        PBAR();
        MFMA_Q(0, 1, b1);
        PBAR();
        // phase 7: read buf1.A1; stage b1.B0<-ktb; acc[1][1]
        LOAD_A(1, 1);
        stage2(W, &BS[1][0][0], bn, ktb);
        PBAR();
        MFMA_Q(1, 1, b1);
        PBAR();
        // phase 8: (regs only); stage b1.B1<-ktb; acc[1][0]; counted wait
        stage2(W, &BS[1][1][0], bn + 128, ktb);
        PBAR();
        MFMA_Q(1, 0, b0);
        asm volatile("s_waitcnt vmcnt(6)" ::: "memory");
        PBAR();
    }

    // ---- epilogue: C/D layout col=l15, row=quad*4+reg [m89/m91-verified] ----
#pragma unroll
    for (int qn = 0; qn < 2; ++qn)
#pragma unroll
        for (int nf = 0; nf < 2; ++nf) {
            const int n = bn + qn * 128 + wnid * 32 + nf * 16 + l15;
            const float bias_f = bias[n];
#pragma unroll
            for (int qm = 0; qm < 2; ++qm)
#pragma unroll
                for (int mf = 0; mf < 4; ++mf) {
                    const int m0 = bm + qm * 128 + wmid * 64 + mf * 16 + quad * 4;
#pragma unroll
                    for (int r = 0; r < 4; ++r)
                        C[(size_t)(m0 + r) * HID + n] =
                            (__bf16)(acc[qm][qn][mf][nf][r] + bias_f);
                }
        }
}

#undef LOAD_A
#undef LOAD_B
#undef MFMA_Q
#undef PBAR

// ---------------------------------------------------------------------------
// Fallback GEMM (fp32 inputs staged+converted through LDS) for small ws.
// ---------------------------------------------------------------------------
__global__ __launch_bounds__(256)
void gemm_bt_bias_f32in(const float* __restrict__ A,
                        const float* __restrict__ W,
                        const float* __restrict__ bias,
                        __hip_bfloat16* __restrict__ C)
{
    constexpr int K = HID;
    __shared__ __align__(16) __hip_bfloat16 As[128 * LDT];
    __shared__ __align__(16) __hip_bfloat16 Bs[128 * LDT];

    const int tid  = threadIdx.x;
    const int wave = tid >> 6;
    const int lane = tid & 63;
    const int bm = blockIdx.y * 128;
    const int bn = blockIdx.x * 128;
    const int wm = (wave >> 1) * 64;
    const int wn = (wave & 1) * 64;

    floatx4 acc[4][4];
#pragma unroll
    for (int i = 0; i < 4; ++i)
#pragma unroll
        for (int j = 0; j < 4; ++j)
            acc[i][j] = (floatx4)(0.0f);

    const int lr = tid >> 4;
    const int lc = (tid & 15) * 4;

    for (int k0 = 0; k0 < K; k0 += 64) {
#pragma unroll
        for (int qq = 0; qq < 8; ++qq) {
            const int r = lr + qq * 16;
            const float4 a4 = *(const float4*)(A + (size_t)(bm + r) * K + k0 + lc);
            const float4 w4 = *(const float4*)(W + (size_t)(bn + r) * K + k0 + lc);
            bf16x4 av, wv;
            av[0] = (__bf16)a4.x; av[1] = (__bf16)a4.y; av[2] = (__bf16)a4.z; av[3] = (__bf16)a4.w;
            wv[0] = (__bf16)w4.x; wv[1] = (__bf16)w4.y; wv[2] = (__bf16)w4.z; wv[3] = (__bf16)w4.w;
            *(bf16x4*)(As + r * LDT + lc) = av;
            *(bf16x4*)(Bs + r * LDT + lc) = wv;
        }
        __syncthreads();
#pragma unroll
        for (int kk = 0; kk < 2; ++kk) {
            const int krow = kk * 32 + (lane >> 4) * 8;
            const int mrow = wm + (lane & 15);
            const int nrow = wn + (lane & 15);
            bf16x8 af[4], bfr[4];
#pragma unroll
            for (int i = 0; i < 4; ++i) {
                af[i]  = *(const bf16x8*)(As + (mrow + i * 16) * LDT + krow);
                bfr[i] = *(const bf16x8*)(Bs + (nrow + i * 16) * LDT + krow);
            }
#pragma unroll
            for (int mi = 0; mi < 4; ++mi)
#pragma unroll
                for (int ni = 0; ni < 4; ++ni)
                    acc[mi][ni] = __builtin_amdgcn_mfma_f32_16x16x32_bf16(
                        af[mi], bfr[ni], acc[mi][ni], 0, 0, 0);
        }
        __syncthreads();
    }

    const int crow0 = bm + wm + (lane >> 4) * 4;
    const int ccol0 = bn + wn + (lane & 15);
#pragma unroll
    for (int ni = 0; ni < 4; ++ni) {
        const int n = ccol0 + ni * 16;
        const float bias_f = bias[n];
#pragma unroll
        for (int mi = 0; mi < 4; ++mi) {
#pragma unroll
            for (int r = 0; r < 4; ++r) {
                const int m = crow0 + mi * 16 + r;
                C[(size_t)m * HID + n] = __float2bfloat16(acc[mi][ni][r] + bias_f);
            }
        }
    }
}

// ---------------------------------------------------------------------------
// Flash attention v5: QBLK=64, 1024 blocks x 4 waves x 16 Q-rows.
// Theory: v4 was latency-chain-bound (per-tile MFMA+VALU floors are ~5 us but
// v4 ran far above; both pipes idle) with only 8 waves/CU (2 blocks x 4 waves,
// LDS 54K caps residency; grid 512 = exactly 2/CU so a 3rd never fills).
// v5: 40 KiB LDS (LKV 72->64 + ADD-rotation swizzle), 1024 finer blocks ->
// 3-4 blocks/CU resident (12-16 waves), paired b32 V-transpose writes (16
// scalar -> 8), setprio(T5, +4-7% m191), finer causal granularity (-6% work).
// Math identical to v4 -> absmax unchanged.
// ---------------------------------------------------------------------------
__global__ __launch_bounds__(256, 4)
void attn_flash_mfma_v5(const __bf16* __restrict__ q,
                        const __bf16* __restrict__ k,
                        const __bf16* __restrict__ v,
                        float* __restrict__ out)
{
    // byte-addressed, 128B rows, ADD-rotation swizzled (see SWZ)
    __shared__ __align__(16) char Ks[2][64 * 128];   // [n][d]
    __shared__ __align__(16) char Vt[2][64 * 128];   // [d][n]
    __shared__ __align__(16) char Ps[4][16 * 128];   // per-wave P [t][n]

    const int tid  = threadIdx.x;
    const int wave = tid >> 6;
    const int lane = tid & 63;
    const int l15  = lane & 15;
    const int quad = lane >> 4;

    const int bx = blockIdx.x;           // 0..1023
    const int jj = bx & 15;
    const int bt = ((bx >> 8) & 1) ? jj : 15 - jj;  // balanced long/short mix
    const int bh = bx >> 4;              // 0..63
    const int h  = bh & (NHEADS - 1);
    const int b  = bh >> 4;
    const int t0 = bt * 64;

    const __bf16* kbase = k + (size_t)b * N_SZ * HID + h * DHEAD;
    const __bf16* vbase = v + (size_t)b * N_SZ * HID + h * DHEAD;

    // ---- Q row to registers (B-frag of S^T), pre-scaled ----
    bf16x8 qf[2];
    {
        const __bf16* qb = q + (size_t)(b * T_SZ + t0 + wave * 16 + l15) * HID + h * DHEAD;
#pragma unroll
        for (int kk = 0; kk < 2; ++kk) {
            const bf16x8 raw = *(const bf16x8*)(qb + kk * 32 + quad * 8);
#pragma unroll
            for (int j = 0; j < 8; ++j)
                qf[kk][j] = (__bf16)((float)raw[j] * SM_SCALE_LOG2E);
        }
    }

    const int kr  = tid >> 3;            // 0..31 (K stage row)
    const int kce = (tid & 7) * 8;       // K stage col (elems)
    const int vn2 = (tid & 31) * 2;      // V pair row
    const int vd2 = (tid >> 5) * 8;      // V d-chunk (multiple of 8!)

    // ---- stage tile 0 ----
    {
        *(bf16x8*)(&Ks[0][0] + SWZ(kr, kce * 2)) =
            *(const bf16x8*)(kbase + (size_t)kr * HID + kce);
        *(bf16x8*)(&Ks[0][0] + SWZ(kr + 32, kce * 2)) =
            *(const bf16x8*)(kbase + (size_t)(kr + 32) * HID + kce);
        const bf16x8 va = *(const bf16x8*)(vbase + (size_t)vn2 * HID + vd2);
        const bf16x8 vb = *(const bf16x8*)(vbase + (size_t)(vn2 + 1) * HID + vd2);
#pragma unroll
        for (int j = 0; j < 8; ++j) {
            bf16x2 t2; t2[0] = va[j]; t2[1] = vb[j];
            // row = vd2+j; (row&7)==j since vd2 is a multiple of 8
            *(bf16x2*)(&Vt[0][0] + SWZ(vd2 + j, vn2 * 2)) = t2;
        }
    }
    __syncthreads();

    float lsum = 0.f;
    floatx4 oacc[4];
#pragma unroll
    for (int nd = 0; nd < 4; ++nd) oacc[nd] = (floatx4)(0.0f);

    char* pw = &Ps[wave][0];
    const int ntiles = bt + 1;
    const int tq = t0 + wave * 16 + l15;

    for (int it = 0; it < ntiles; ++it) {
        const int bi = it & 1;
        const int n0 = it * 64;

        bf16x8 nk0, nk1, nva, nvb;
        const bool pf = (it + 1 < ntiles);
        if (pf) {
            const int nn0 = n0 + 64;
            nk0 = *(const bf16x8*)(kbase + (size_t)(nn0 + kr) * HID + kce);
            nk1 = *(const bf16x8*)(kbase + (size_t)(nn0 + kr + 32) * HID + kce);
            nva = *(const bf16x8*)(vbase + (size_t)(nn0 + vn2) * HID + vd2);
            nvb = *(const bf16x8*)(vbase + (size_t)(nn0 + vn2 + 1) * HID + vd2);
        }

        // ---- S^T = K @ Q^T : C/D col=t(l15), row=n(quad*4+r) ----
        floatx4 st[4];
#pragma unroll
        for (int ni = 0; ni < 4; ++ni) st[ni] = (floatx4)(0.0f);
        const char* ksb = &Ks[bi][0];
        __builtin_amdgcn_s_setprio(1);
#pragma unroll
        for (int kk = 0; kk < 2; ++kk) {
            const int cb = kk * 64 + quad * 16;
#pragma unroll
            for (int ni = 0; ni < 4; ++ni) {
                const bf16x8 af = *(const bf16x8*)(ksb + SWZ(ni * 16 + l15, cb));
                st[ni] = __builtin_amdgcn_mfma_f32_16x16x32_bf16(af, qf[kk], st[ni], 0, 0, 0);
            }
        }
        __builtin_amdgcn_s_setprio(0);

        // ---- shift-free softmax; packed b64 P-writes; lane-local lsum ----
        const bool msk = (it == bt);
#pragma unroll
        for (int ni = 0; ni < 4; ++ni) {
            bf16x4 pk;
#pragma unroll
            for (int r = 0; r < 4; ++r) {
                float p = exp2f(st[ni][r]);
                if (msk) {
                    const int nn = n0 + ni * 16 + quad * 4 + r;
                    p = (nn > tq) ? 0.f : p;
                }
                lsum += p;
                pk[r] = (__bf16)p;
            }
            *(bf16x4*)(pw + SWZ(l15, ni * 32 + quad * 8)) = pk;
        }

        // ---- O^T += Vt @ P : C/D col=t(l15), row=d(quad*4+r) ----
        const char* vtb = &Vt[bi][0];
        __builtin_amdgcn_s_setprio(1);
#pragma unroll
        for (int kk = 0; kk < 2; ++kk) {
            const int cb = kk * 64 + quad * 16;
            const bf16x8 bp = *(const bf16x8*)(pw + SWZ(l15, cb));
#pragma unroll
            for (int nd = 0; nd < 4; ++nd) {
                const bf16x8 av = *(const bf16x8*)(vtb + SWZ(nd * 16 + l15, cb));
                oacc[nd] = __builtin_amdgcn_mfma_f32_16x16x32_bf16(av, bp, oacc[nd], 0, 0, 0);
            }
        }
        __builtin_amdgcn_s_setprio(0);

        if (pf) {
            char* kd = &Ks[bi ^ 1][0];
            char* vd = &Vt[bi ^ 1][0];
            *(bf16x8*)(kd + SWZ(kr, kce * 2)) = nk0;
            *(bf16x8*)(kd + SWZ(kr + 32, kce * 2)) = nk1;
#pragma unroll
            for (int j = 0; j < 8; ++j) {
                bf16x2 t2; t2[0] = nva[j]; t2[1] = nvb[j];
                *(bf16x2*)(vd + SWZ(vd2 + j, vn2 * 2)) = t2;
            }
        }
        __syncthreads();
    }

    // ---- epilogue ----
    lsum += __shfl_xor(lsum, 16, 64);
    lsum += __shfl_xor(lsum, 32, 64);
    {
        const float invl = 1.0f / lsum;
        float* ob = out + (size_t)(b * T_SZ + tq) * HID + h * DHEAD + quad * 4;
#pragma unroll
        for (int nd = 0; nd < 4; ++nd) {
            float4 o4;
            o4.x = oacc[nd][0] * invl;
            o4.y = oacc[nd][1] * invl;
            o4.z = oacc[nd][2] * invl;
            o4.w = oacc[nd][3] * invl;
            *(float4*)(ob + nd * 16) = o4;
        }
    }
}

extern "C" void kernel_launch(void* const* d_in, const int* in_sizes, int n_in,
                              void* d_out, int out_size, void* d_ws, size_t ws_size,
                              hipStream_t stream) {
    const float* x   = (const float*)d_in[0];
    const float* enc = (const float*)d_in[1];
    const float* Wq  = (const float*)d_in[2];
    const float* bq  = (const float*)d_in[3];
    const float* Wk  = (const float*)d_in[4];
    const float* bk  = (const float*)d_in[5];
    const float* Wv  = (const float*)d_in[6];
    const float* bv  = (const float*)d_in[7];
    float* out = (float*)d_out;

    char* ws = (char*)d_ws;
    const size_t MiB = 1024 * 1024;
    __bf16* q_ws = (__bf16*)(ws);
    __bf16* k_ws = (__bf16*)(ws + 8 * MiB);
    __bf16* v_ws = (__bf16*)(ws + 16 * MiB);

    const dim3 blk(256);
    if (ws_size >= 46 * MiB) {
        __bf16* xb  = (__bf16*)(ws + 24 * MiB);
        __bf16* eb  = (__bf16*)(ws + 32 * MiB);
        __bf16* wqb = (__bf16*)(ws + 40 * MiB);
        __bf16* wkb = (__bf16*)(ws + 42 * MiB);
        __bf16* wvb = (__bf16*)(ws + 44 * MiB);
        cvt5_f32_bf16<<<dim3(704), blk, 0, stream>>>(x, enc, Wq, Wk, Wv,
                                                     xb, eb, wqb, wkb, wvb);
        gemm3_256_8ph<<<dim3(192), dim3(512), 0, stream>>>(
            xb, eb, wqb, wkb, wvb, bq, bk, bv, q_ws, k_ws, v_ws);
    } else {
        const dim3 gg(HID / 128, (B_SZ * T_SZ) / 128);
        gemm_bt_bias_f32in<<<gg, blk, 0, stream>>>(x,   Wq, bq, (__hip_bfloat16*)q_ws);
        gemm_bt_bias_f32in<<<gg, blk, 0, stream>>>(enc, Wk, bk, (__hip_bfloat16*)k_ws);
        gemm_bt_bias_f32in<<<gg, blk, 0, stream>>>(enc, Wv, bv, (__hip_bfloat16*)v_ws);
    }

    attn_flash_mfma_v5<<<dim3(1024), blk, 0, stream>>>(q_ws, k_ws, v_ws, out);
}